// Round 3
// baseline (434.174 us; speedup 1.0000x reference)
//
#include <hip/hip_runtime.h>

// Problem constants (fixed by setup_inputs):
//   a_arc, s_arc : [64, 1024, 1024] f32
//   adds, pos    : [64, 1024] int32 in [0, 50)
constexpr int NPOS  = 50;
constexpr int NBINS = NPOS * NPOS;   // 2500
constexpr int SL    = 1024;
constexpr int BZ    = 64;
constexpr float ALPHA = 0.3f;

constexpr int NTHREADS       = 256;
constexpr int ROWS_PER_BLOCK = 32;
constexpr int BLOCKS_PER_B   = SL / ROWS_PER_BLOCK;   // 32
constexpr int NBLOCKS        = BZ * BLOCKS_PER_B;     // 2048

// ---------------------------------------------------------------------------
// Kernel 1: LDS histogram of a_arc keyed by adds[b,i]*50 + adds[b,j].
// Same structure as the verified round-0 kernel, but each wave-instruction
// spans FOUR rows (lane>>4 selects the row, lane&15 the float4 column), so
// the 64 lanes of an atomic instruction hit 4 different 50-bin slices:
// same-address multiplicity drops ~5x -> ~1.15, killing the 200-cyc/instr
// LDS-atomic serialization measured in round 0.
// ---------------------------------------------------------------------------
__global__ __launch_bounds__(NTHREADS) void hist_kernel(
    const float* __restrict__ a, const int* __restrict__ adds,
    float* __restrict__ g_hist) {
  __shared__ float shist[NBINS];   // 10 KB block-private histogram
  __shared__ int   adds_s[SL];     // 4 KB

  const int tid = threadIdx.x;
  const int b   = blockIdx.x / BLOCKS_PER_B;
  const int i0  = (blockIdx.x % BLOCKS_PER_B) * ROWS_PER_BLOCK;

  ((int4*)adds_s)[tid] = ((const int4*)(adds + (size_t)b * SL))[tid];
  for (int k = tid; k < NBINS; k += NTHREADS) shist[k] = 0.0f;
  __syncthreads();

  const int lane  = tid & 63;
  const int wid   = tid >> 6;
  const int r_off = lane >> 4;                 // 0..3: row within the 4-row group
  const int c00   = wid * 16 + (lane & 15);    // float4-column base, 0..63

  // Hoist this thread's 16 column bins into registers (static indexing).
  int cj[4][4];
  #pragma unroll
  for (int cc = 0; cc < 4; ++cc) {
    const int j0 = (c00 + cc * 64) * 4;
    #pragma unroll
    for (int k = 0; k < 4; ++k) cj[cc][k] = adds_s[j0 + k];
  }

  const float4* __restrict__ A =
      (const float4*)(a + ((size_t)b * SL + i0) * SL);

  for (int rr = 0; rr < ROWS_PER_BLOCK / 4; ++rr) {   // 8 four-row groups
    const int r    = rr * 4 + r_off;                  // row within block
    const int base = adds_s[i0 + r] * NPOS;           // 4 distinct per wave
    #pragma unroll
    for (int cc = 0; cc < 4; ++cc) {
      const int cv = c00 + cc * 64;                   // float4-col, 0..255
      const float4 v = A[(size_t)r * (SL / 4) + cv];
      atomicAdd(&shist[base + cj[cc][0]], v.x);
      atomicAdd(&shist[base + cj[cc][1]], v.y);
      atomicAdd(&shist[base + cj[cc][2]], v.z);
      atomicAdd(&shist[base + cj[cc][3]], v.w);
    }
  }
  __syncthreads();

  // Flush block-private histogram to global (d_ws, pre-zeroed on stream).
  for (int k = tid; k < NBINS; k += NTHREADS) {
    const float v = shist[k];
    if (v != 0.0f) atomicAdd(&g_hist[k], v);
  }
}

// ---------------------------------------------------------------------------
// Kernel 2: out = s_arc + ALPHA * sigmoid(hist)[pos[b,i]*50 + pos[b,j]]
// Measured at ~6.1 TB/s (HBM roofline) in round 0 — unchanged.
// ---------------------------------------------------------------------------
__global__ __launch_bounds__(NTHREADS) void apply_kernel(
    const float* __restrict__ s, const int* __restrict__ pos,
    const float* __restrict__ g_hist, float* __restrict__ out) {
  __shared__ float sig[NBINS];
  __shared__ int   pos_s[SL];

  const int tid = threadIdx.x;
  const int b   = blockIdx.x / BLOCKS_PER_B;
  const int i0  = (blockIdx.x % BLOCKS_PER_B) * ROWS_PER_BLOCK;

  ((int4*)pos_s)[tid] = ((const int4*)(pos + (size_t)b * SL))[tid];
  for (int k = tid; k < NBINS; k += NTHREADS) {
    const float h = g_hist[k];
    sig[k] = 1.0f / (1.0f + __expf(-h));
  }
  __syncthreads();

  const int4 pj = ((const int4*)pos_s)[tid];
  const size_t rowoff = ((size_t)b * SL + i0) * SL;
  const float4* __restrict__ srow = (const float4*)(s + rowoff);
  float4* __restrict__ orow = (float4*)(out + rowoff);

  for (int r = 0; r < ROWS_PER_BLOCK; ++r) {
    const int base = pos_s[i0 + r] * NPOS;    // wave-uniform broadcast
    const float4 sv = srow[(size_t)r * (SL / 4) + tid];
    float4 ov;
    ov.x = sv.x + ALPHA * sig[base + pj.x];
    ov.y = sv.y + ALPHA * sig[base + pj.y];
    ov.z = sv.z + ALPHA * sig[base + pj.z];
    ov.w = sv.w + ALPHA * sig[base + pj.w];
    orow[(size_t)r * (SL / 4) + tid] = ov;
  }
}

extern "C" void kernel_launch(void* const* d_in, const int* in_sizes, int n_in,
                              void* d_out, int out_size, void* d_ws, size_t ws_size,
                              hipStream_t stream) {
  const float* a_arc = (const float*)d_in[0];
  const float* s_arc = (const float*)d_in[1];
  const int*   adds  = (const int*)d_in[2];
  const int*   pos   = (const int*)d_in[3];
  float* out    = (float*)d_out;
  float* g_hist = (float*)d_ws;   // NBINS floats = 10 KB scratch

  // d_ws is NOT re-poisoned between timed replays; zero it each call.
  hipMemsetAsync(g_hist, 0, NBINS * sizeof(float), stream);

  hist_kernel <<<NBLOCKS, NTHREADS, 0, stream>>>(a_arc, adds, g_hist);
  apply_kernel<<<NBLOCKS, NTHREADS, 0, stream>>>(s_arc, pos, g_hist, out);
}

// Round 4
// 188.513 us; speedup vs baseline: 2.3032x; 2.3032x over previous
//
#include <hip/hip_runtime.h>

// Problem constants (fixed by setup_inputs):
//   a_arc, s_arc : [64, 1024, 1024] f32
//   adds, pos    : [64, 1024] int32 in [0, 50)
constexpr int NPOS  = 50;
constexpr int NBINS = NPOS * NPOS;   // 2500
constexpr int SL    = 1024;
constexpr int BZ    = 64;
constexpr float ALPHA = 0.3f;

// ---------------- hist kernel config ----------------
constexpr int H_THREADS  = 256;                 // 1 column per thread
constexpr int COLCHUNKS  = 4;                   // 4 * 256 = 1024 columns
constexpr int ROWSPLITS  = 2;                   // 512 rows per block
constexpr int H_ROWS     = SL / ROWSPLITS;      // 512
constexpr int H_BLOCKS   = BZ * COLCHUNKS * ROWSPLITS;   // 512 (= 2 blocks/CU)

// ---------------- apply kernel config ----------------
constexpr int A_THREADS       = 256;
constexpr int ROWS_PER_BLOCK  = 32;
constexpr int BLOCKS_PER_B    = SL / ROWS_PER_BLOCK;     // 32
constexpr int A_BLOCKS        = BZ * BLOCKS_PER_B;       // 2048

// ---------------------------------------------------------------------------
// Kernel 1: histogram with ZERO atomics in the main loop.
// Thread t owns column j = cc*256 + t (column-bin q fixed). The wave walks
// rows together, so row-bin p = adds[b,row] is wave-uniform. Accumulator
// accL[p][t] is exclusive to thread t -> plain LDS read/add/write, address
// p*256+t is bank-conflict-free. Round-0/2 showed LDS atomicAdd costs
// ~3.1 cyc/lane regardless of address pattern -> atomics removed entirely.
// ---------------------------------------------------------------------------
__global__ __launch_bounds__(H_THREADS) void hist_kernel(
    const float* __restrict__ a, const int* __restrict__ adds,
    float* __restrict__ g_hist) {
  __shared__ float accL[NPOS][H_THREADS];   // 51.2 KB, [row-bin][thread]
  __shared__ int   adds_s[SL];              // 4 KB
  __shared__ int   cnt2[NPOS];              // per-q column counts
  __shared__ int   off2s[NPOS];             // immutable start offsets
  __shared__ int   off2m[NPOS];             // mutable scatter cursors
  __shared__ int   order2[H_THREADS];       // thread ids sorted by q

  const int tid    = threadIdx.x;
  const int b      = blockIdx.x / (COLCHUNKS * ROWSPLITS);
  const int rem    = blockIdx.x % (COLCHUNKS * ROWSPLITS);
  const int cc     = rem / ROWSPLITS;
  const int rsplit = rem % ROWSPLITS;
  const int i0     = rsplit * H_ROWS;

  // Stage adds row; zero accumulators and counters.
  ((int4*)adds_s)[tid] = ((const int4*)(adds + (size_t)b * SL))[tid];
  #pragma unroll
  for (int p = 0; p < NPOS; ++p) accL[p][tid] = 0.0f;
  if (tid < NPOS) cnt2[tid] = 0;
  __syncthreads();

  const int j = cc * H_THREADS + tid;       // this thread's column
  const int q = adds_s[j];                  // its fixed column-bin

  // --- main loop: 512 rows, 16-row software pipeline ---
  const float* __restrict__ P = a + ((size_t)b * SL + i0) * SL + j;
  for (int r0 = 0; r0 < H_ROWS; r0 += 16) {
    float v[16];
    #pragma unroll
    for (int k = 0; k < 16; ++k)            // 16 independent coalesced loads
      v[k] = P[(size_t)(r0 + k) * SL];
    int bs[16];
    #pragma unroll
    for (int k4 = 0; k4 < 4; ++k4) {        // wave-uniform broadcast reads
      const int4 b4 = *(const int4*)&adds_s[i0 + r0 + k4 * 4];
      bs[k4 * 4 + 0] = b4.x; bs[k4 * 4 + 1] = b4.y;
      bs[k4 * 4 + 2] = b4.z; bs[k4 * 4 + 3] = b4.w;
    }
    #pragma unroll
    for (int k = 0; k < 16; ++k)            // exclusive slot: no atomics
      accL[bs[k]][tid] += v[k];
  }

  // --- counting sort of the 256 column-q values (tiny) ---
  atomicAdd(&cnt2[q], 1);
  __syncthreads();
  if (tid == 0) {
    int run = 0;
    for (int c = 0; c < NPOS; ++c) { off2s[c] = run; off2m[c] = run; run += cnt2[c]; }
  }
  __syncthreads();
  order2[atomicAdd(&off2m[q], 1)] = tid;
  __syncthreads();

  // --- reduce: bin (p,q) = sum of accL[p][t] over threads t with q_t == q,
  //     one global atomic per (block, bin) ---
  for (int bin = tid; bin < NBINS; bin += H_THREADS) {
    const int p  = bin / NPOS;
    const int qq = bin % NPOS;
    const int s0 = off2s[qq];
    const int n  = cnt2[qq];
    float s = 0.0f;
    for (int k = 0; k < n; ++k) s += accL[p][order2[s0 + k]];
    atomicAdd(&g_hist[bin], s);
  }
}

// ---------------------------------------------------------------------------
// Kernel 2: out = s_arc + ALPHA * sigmoid(hist)[pos[b,i]*50 + pos[b,j]]
// Measured at ~6.1 TB/s (HBM roofline) — unchanged from the passing version.
// ---------------------------------------------------------------------------
__global__ __launch_bounds__(A_THREADS) void apply_kernel(
    const float* __restrict__ s, const int* __restrict__ pos,
    const float* __restrict__ g_hist, float* __restrict__ out) {
  __shared__ float sig[NBINS];
  __shared__ int   pos_s[SL];

  const int tid = threadIdx.x;
  const int b   = blockIdx.x / BLOCKS_PER_B;
  const int i0  = (blockIdx.x % BLOCKS_PER_B) * ROWS_PER_BLOCK;

  ((int4*)pos_s)[tid] = ((const int4*)(pos + (size_t)b * SL))[tid];
  for (int k = tid; k < NBINS; k += A_THREADS) {
    const float h = g_hist[k];
    sig[k] = 1.0f / (1.0f + __expf(-h));
  }
  __syncthreads();

  const int4 pj = ((const int4*)pos_s)[tid];
  const size_t rowoff = ((size_t)b * SL + i0) * SL;
  const float4* __restrict__ srow = (const float4*)(s + rowoff);
  float4* __restrict__ orow = (float4*)(out + rowoff);

  for (int r = 0; r < ROWS_PER_BLOCK; ++r) {
    const int base = pos_s[i0 + r] * NPOS;    // wave-uniform broadcast
    const float4 sv = srow[(size_t)r * (SL / 4) + tid];
    float4 ov;
    ov.x = sv.x + ALPHA * sig[base + pj.x];
    ov.y = sv.y + ALPHA * sig[base + pj.y];
    ov.z = sv.z + ALPHA * sig[base + pj.z];
    ov.w = sv.w + ALPHA * sig[base + pj.w];
    orow[(size_t)r * (SL / 4) + tid] = ov;
  }
}

extern "C" void kernel_launch(void* const* d_in, const int* in_sizes, int n_in,
                              void* d_out, int out_size, void* d_ws, size_t ws_size,
                              hipStream_t stream) {
  const float* a_arc = (const float*)d_in[0];
  const float* s_arc = (const float*)d_in[1];
  const int*   adds  = (const int*)d_in[2];
  const int*   pos   = (const int*)d_in[3];
  float* out    = (float*)d_out;
  float* g_hist = (float*)d_ws;   // NBINS floats = 10 KB scratch

  // d_ws is NOT re-poisoned between timed replays; zero it each call.
  hipMemsetAsync(g_hist, 0, NBINS * sizeof(float), stream);

  hist_kernel <<<H_BLOCKS, H_THREADS, 0, stream>>>(a_arc, adds, g_hist);
  apply_kernel<<<A_BLOCKS, A_THREADS, 0, stream>>>(s_arc, pos, g_hist, out);
}